// Round 1
// baseline (183.994 us; speedup 1.0000x reference)
//
#include <hip/hip_runtime.h>
#include <math.h>
#include <limits.h>

namespace {
constexpr int kFeat = 112;
constexpr int kBatch = 256;
constexpr int kTotal = 96981;
constexpr int kStride = 116;      // /4 -> float4-aligned columns (rw%4==0 for all ratios)
constexpr int kNT = 512;          // 8 waves; 3 blocks/CU (LDS-limited)
constexpr int kL = 4;             // per-thread top-L candidate cache for NMS re-passes
constexpr int kRH[13] = {16,12,20,24,20,28,32,24,40,28,40,28,36};
constexpr int kRW[13] = {16,20,12,24,28,20,32,40,24,40,28,36,28};
constexpr int kOff[13] = {0,9409,18802,28195,36116,44021,51926,58487,64984,71481,77686,83891,90436};
}

struct NmsShared {
  float rs[kNT / 64];
  int   ri[kNT / 64];
  float shS; int shI;
  float pX0[3], pY0[3], pX1[3], pY1[3], pA[3];
};

__device__ __forceinline__ void block_argmax(float s, int i, NmsShared* ns) {
  __syncthreads();                       // protect rs/ri reuse across passes
#pragma unroll
  for (int off = 32; off > 0; off >>= 1) {
    const float s2 = __shfl_down(s, off, 64);
    const int   i2 = __shfl_down(i, off, 64);
    if (s2 > s || (s2 == s && i2 < i)) { s = s2; i = i2; }
  }
  const int wave = threadIdx.x >> 6;
  if ((threadIdx.x & 63) == 0) { ns->rs[wave] = s; ns->ri[wave] = i; }
  __syncthreads();
  if (threadIdx.x == 0) {
    float bs = ns->rs[0]; int bi = ns->ri[0];
#pragma unroll
    for (int w = 1; w < kNT / 64; ++w)
      if (ns->rs[w] > bs || (ns->rs[w] == bs && ns->ri[w] < bi)) { bs = ns->rs[w]; bi = ns->ri[w]; }
    ns->shS = bs; ns->shI = bi;
  }
  __syncthreads();
}

// Build 113x113 inclusive SAT (border row/col 0) in LDS, stride 116.
__device__ void build_sat(const float* __restrict__ xb, float* __restrict__ sat) {
  const int tid = threadIdx.x;
  for (int j = tid; j < kStride; j += kNT) sat[j] = 0.f;          // row 0 (+pad)
  for (int r = tid; r < 113; r += kNT) sat[r * kStride] = 0.f;    // col 0
  const float4* x4 = (const float4*)xb;                            // 12544%4==0, base aligned
  for (int i = tid; i < (kFeat * kFeat) / 4; i += kNT) {
    const float4 v = x4[i];
    const int r = i / (kFeat / 4);
    const int c = (i - r * (kFeat / 4)) * 4;
    float* dst = sat + (r + 1) * kStride + c + 1;
    dst[0] = v.x; dst[1] = v.y; dst[2] = v.z; dst[3] = v.w;
  }
  __syncthreads();
  // row inclusive scans: one wave per row, lanes = columns (conflict-free)
  const int wave = tid >> 6, lane = tid & 63;
  for (int r = 1 + wave; r <= kFeat; r += kNT / 64) {
    float* row = sat + r * kStride;
    float v = row[1 + lane];                       // cols 1..64
#pragma unroll
    for (int d = 1; d < 64; d <<= 1) { const float u = __shfl_up(v, d, 64); if (lane >= d) v += u; }
    row[1 + lane] = v;
    const float tot = __shfl(v, 63, 64);
    const int c = 65 + lane;                       // cols 65..112
    float w = (c <= kFeat) ? row[c] : 0.f;
#pragma unroll
    for (int d = 1; d < 64; d <<= 1) { const float u = __shfl_up(w, d, 64); if (lane >= d) w += u; }
    if (c <= kFeat) row[c] = w + tot;
  }
  __syncthreads();
  // column scans, 4 segments of 28 rows: serial chain cut 112 -> 28
  const int seg = tid / kFeat;            // 0..3 for tid < 448
  const int col = tid - seg * kFeat + 1;  // 1..112
  if (tid < 4 * kFeat) {
    const int r0 = seg * 28 + 1;
    float s = 0.f;
    for (int r = r0; r < r0 + 28; ++r) { s += sat[r * kStride + col]; sat[r * kStride + col] = s; }
  }
  __syncthreads();
  float off = 0.f;
  if (tid < 4 * kFeat && seg > 0) {
#pragma unroll
    for (int s2 = 1; s2 <= 3; ++s2)
      if (s2 <= seg) off += sat[(28 * s2) * kStride + col];
  }
  __syncthreads();
  if (tid < 4 * kFeat && seg > 0) {
    const int r0 = seg * 28 + 1;
    for (int r = r0; r < r0 + 28; ++r) sat[r * kStride + col] += off;
  }
  __syncthreads();
}

// Global order used by the reference: score desc, then lowest index on ties.
__device__ __forceinline__ bool cand_better(float s, int i, float s2, int i2) {
  return s > s2 || (s == s2 && i < i2);
}

// Keep cs/ci sorted by cand_better (best first). One insertion-sort bubble pass.
__device__ __forceinline__ void topl_insert(float (&cs)[kL], int (&ci)[kL], float s, int i) {
  if (!cand_better(s, i, cs[kL - 1], ci[kL - 1])) return;
  cs[kL - 1] = s; ci[kL - 1] = i;
#pragma unroll
  for (int c = kL - 2; c >= 0; --c) {
    if (cand_better(cs[c + 1], ci[c + 1], cs[c], ci[c])) {
      const float ts = cs[c]; const int ti = ci[c];
      cs[c] = cs[c + 1]; ci[c] = ci[c + 1];
      cs[c + 1] = ts; ci[c + 1] = ti;
    }
  }
}

// idx -> window geometry (same arithmetic as pick_store / reference coords).
template<int RB, int RE>
__device__ __forceinline__ void decode_geom(int pi, float& x0, float& y0,
                                            float& x1, float& y1, float& a) {
  x0 = 0.f; y0 = 0.f; x1 = 0.f; y1 = 0.f; a = 0.f;
#pragma unroll
  for (int rr = RB; rr < RE; ++rr) {
    const int nr = kFeat - kRH[rr] + 1, nc = kFeat - kRW[rr] + 1;
    if (pi >= kOff[rr] && pi < kOff[rr] + nr * nc) {
      const int l = pi - kOff[rr];
      const int xi = l / nc, yi = l - xi * nc;
      const float x0u = xi * 4.0f - 1.0f, y0u = yi * 4.0f - 1.0f;
      x1 = x0u + kRH[rr] * 4.0f; y1 = y0u + kRW[rr] * 4.0f;
      x0 = fmaxf(x0u, 0.0f); y0 = fmaxf(y0u, 0.0f);
      a = (x1 - x0 + 1.0f) * (y1 - y0 + 1.0f);
    }
  }
}

template<int RB, int RE>
__device__ __forceinline__ void pick_store(NmsShared* ns, int k, int slot,
                                           float* __restrict__ out_idx,
                                           float* __restrict__ out_sc, int b) {
  if (threadIdx.x == 0) {
    const int pi = ns->shI;
#pragma unroll
    for (int rr = RB; rr < RE; ++rr) {
      const int nr = kFeat - kRH[rr] + 1, nc = kFeat - kRW[rr] + 1;
      if (pi >= kOff[rr] && pi < kOff[rr] + nr * nc) {
        const int l = pi - kOff[rr];
        const int xi = l / nc, yi = l - xi * nc;
        const float x0u = xi * 4.0f - 1.0f, y0u = yi * 4.0f - 1.0f;
        const float x1 = x0u + kRH[rr] * 4.0f, y1 = y0u + kRW[rr] * 4.0f;
        const float x0 = fmaxf(x0u, 0.0f), y0 = fmaxf(y0u, 0.0f);
        ns->pX0[k] = x0; ns->pY0[k] = y0; ns->pX1[k] = x1; ns->pY1[k] = y1;
        ns->pA[k] = (x1 - x0 + 1.0f) * (y1 - y0 + 1.0f);
      }
    }
    out_idx[b * 7 + slot + k] = (float)pi;
    out_sc [b * 7 + slot + k] = ns->shS;
  }
  __syncthreads();
}

// Score this group's ratios once (write wb, keep per-thread top-L candidates),
// then NP greedy-NMS picks testing only the candidate list (exact: fallback
// rescan if a thread's whole list is suppressed).
template<int RB, int RE, int NP, int SLOT>
__device__ void run_group(const float* __restrict__ sat, NmsShared* ns,
                          float* __restrict__ wb,
                          float* __restrict__ out_idx, float* __restrict__ out_sc, int b) {
  const int tid = threadIdx.x;
  float cs[kL]; int ci[kL];
#pragma unroll
  for (int c = 0; c < kL; ++c) { cs[c] = -INFINITY; ci[c] = INT_MAX; }

  // ---- pass 0: quad-vectorized scoring, aligned ds_read_b128, top-L tracking ----
#pragma unroll
  for (int rr = RB; rr < RE; ++rr) {
    const int rh = kRH[rr], rw = kRW[rr];
    const int nr = kFeat - rh + 1, nc = kFeat - rw + 1;
    const int nqy = (nc + 3) >> 2;
    const float inv = 1.0f / (float)(rh * rw);
    for (int q = tid; q < nr * nqy; q += kNT) {
      const int xi = q / nqy, qy = q - xi * nqy;     // nqy compile-time -> magic mul
      const int yi0 = qy << 2;
      const float* u = sat + xi * kStride;
      const float* d = u + rh * kStride;
      const float4 U0 = *(const float4*)(u + yi0);
      const float4 U1 = *(const float4*)(u + yi0 + rw);
      const float4 D0 = *(const float4*)(d + yi0);
      const float4 D1 = *(const float4*)(d + yi0 + rw);
      const float s0 = (D1.x - U1.x - D0.x + U0.x) * inv;
      const float s1 = (D1.y - U1.y - D0.y + U0.y) * inv;
      const float s2 = (D1.z - U1.z - D0.z + U0.z) * inv;
      const float s3 = (D1.w - U1.w - D0.w + U0.w) * inv;
      const int gi0 = kOff[rr] + xi * nc + yi0;
      float* w = wb + gi0;
      const int rem = nc - yi0;                      // >= 1
      w[0] = s0; topl_insert(cs, ci, s0, gi0);
      if (rem > 1) { w[1] = s1; topl_insert(cs, ci, s1, gi0 + 1); }
      if (rem > 2) { w[2] = s2; topl_insert(cs, ci, s2, gi0 + 2); }
      if (rem > 3) { w[3] = s3; topl_insert(cs, ci, s3, gi0 + 3); }
    }
  }

  // ---- pick 0: per-thread best is cs[0] ----
  block_argmax(cs[0], ci[0], ns);
  pick_store<RB, RE>(ns, 0, SLOT, out_idx, out_sc, b);

  // ---- picks 1..NP-1: candidate-list NMS ----
  // iou > 0.25  <=>  5*inter > A + pa   (integer-valued floats -> exact).
  // Self-window has inter == A == pa -> always suppressed.
  // Thread's alive-max == first non-suppressed entry of its sorted top-L
  // (anything outside the list is <= cs[kL-1] in (score, idx) order).
  // If the whole list is suppressed, exact fallback: rescan own windows from SAT.
  for (int k = 1; k < NP; ++k) {
    float px0[NP], py0[NP], px1[NP], py1[NP], pa[NP];
#pragma unroll
    for (int p = 0; p < NP; ++p) {
      if (p < k) { px0[p] = ns->pX0[p]; py0[p] = ns->pY0[p]; px1[p] = ns->pX1[p];
                   py1[p] = ns->pY1[p]; pa[p] = ns->pA[p]; }
    }

    float best = -INFINITY; int bi = INT_MAX; bool found = false;
#pragma unroll
    for (int c = 0; c < kL; ++c) {
      if (!found) {
        float x0, y0, x1, y1, a;
        decode_geom<RB, RE>(ci[c], x0, y0, x1, y1, a);
        bool sup = false;
#pragma unroll
        for (int p = 0; p < NP; ++p) {
          if (p < k) {
            const float wx = fminf(x1, px1[p]) - fmaxf(x0, px0[p]) + 1.0f;
            const float hy = fminf(y1, py1[p]) - fmaxf(y0, py0[p]) + 1.0f;
            sup = sup | ((wx >= 0.0f) & (hy >= 0.0f) & (5.0f * wx * hy > a + pa[p]));
          }
        }
        if (!sup) { best = cs[c]; bi = ci[c]; found = true; }
      }
    }

    if (!found) {
      // cold exact fallback: this thread rescans its own windows from the SAT
      // (thread-local loop, no barriers -> safe under divergence)
#pragma unroll
      for (int rr = RB; rr < RE; ++rr) {
        const int rh = kRH[rr], rw = kRW[rr];
        const int nr = kFeat - rh + 1, nc = kFeat - rw + 1;
        const int nqy = (nc + 3) >> 2;
        const float inv = 1.0f / (float)(rh * rw);
        for (int q = tid; q < nr * nqy; q += kNT) {
          const int xi = q / nqy, qy = q - xi * nqy;
          const int yi0 = qy << 2;
          const float* u = sat + xi * kStride;
          const float* d = u + rh * kStride;
          const float4 U0 = *(const float4*)(u + yi0);
          const float4 U1 = *(const float4*)(u + yi0 + rw);
          const float4 D0 = *(const float4*)(d + yi0);
          const float4 D1 = *(const float4*)(d + yi0 + rw);
          float s4[4];
          s4[0] = (D1.x - U1.x - D0.x + U0.x) * inv;
          s4[1] = (D1.y - U1.y - D0.y + U0.y) * inv;
          s4[2] = (D1.z - U1.z - D0.z + U0.z) * inv;
          s4[3] = (D1.w - U1.w - D0.w + U0.w) * inv;
          const float X0u = xi * 4.0f - 1.0f;
          const float X1 = X0u + rh * 4.0f;
          const float X0 = fmaxf(X0u, 0.0f);
          const float Ax = X1 - X0 + 1.0f;
          float wxp[NP];
#pragma unroll
          for (int p = 0; p < NP; ++p)
            if (p < k) wxp[p] = fminf(X1, px1[p]) - fmaxf(X0, px0[p]) + 1.0f;
          const int gi0 = kOff[rr] + xi * nc + yi0;
          const int rem = nc - yi0;
#pragma unroll
          for (int j = 0; j < 4; ++j) {
            if (j >= rem) break;
            const float Y0u = (yi0 + j) * 4.0f - 1.0f;
            const float Y1 = Y0u + rw * 4.0f;
            const float Y0 = fmaxf(Y0u, 0.0f);
            const float A = Ax * (Y1 - Y0 + 1.0f);
            bool alive = true;
#pragma unroll
            for (int p = 0; p < NP; ++p) {
              if (p >= k) break;
              const float hy = fminf(Y1, py1[p]) - fmaxf(Y0, py0[p]) + 1.0f;
              const bool sup = (wxp[p] >= 0.0f) & (hy >= 0.0f) &
                               (5.0f * wxp[p] * hy > A + pa[p]);
              alive &= !sup;
            }
            if (alive && s4[j] > best) { best = s4[j]; bi = gi0 + j; }
          }
        }
      }
    }

    block_argmax(best, bi, ns);
    pick_store<RB, RE>(ns, k, SLOT, out_idx, out_sc, b);
  }
}

__global__ __launch_bounds__(kNT, 6) void appm_fused(const float* __restrict__ x,
                                                     float* __restrict__ win,
                                                     float* __restrict__ out_idx,
                                                     float* __restrict__ out_sc) {
  __shared__ __align__(16) float sat[113 * kStride];   // 52,432 B
  __shared__ NmsShared ns;
  const int b = blockIdx.x / 3;
  const int t = blockIdx.x % 3;      // group id: each block handles one NMS group

  build_sat(x + (size_t)b * kFeat * kFeat, sat);

  float* wb = win + (size_t)b * kTotal;
  if (t == 0)       run_group<0, 3, 2, 0>(sat, &ns, wb, out_idx, out_sc, b);
  else if (t == 1)  run_group<3, 6, 3, 2>(sat, &ns, wb, out_idx, out_sc, b);
  else              run_group<6, 13, 2, 5>(sat, &ns, wb, out_idx, out_sc, b);
}

extern "C" void kernel_launch(void* const* d_in, const int* in_sizes, int n_in,
                              void* d_out, int out_size, void* d_ws, size_t ws_size,
                              hipStream_t stream) {
  const float* x = (const float*)d_in[0];
  float* out     = (float*)d_out;
  float* out_idx = out;                      // (256,7) indices as float values
  float* out_sc  = out + kBatch * 7;         // (256,7) picked scores
  float* win     = out + 2 * kBatch * 7;     // (256,96981) window scores

  appm_fused<<<kBatch * 3, kNT, 0, stream>>>(x, win, out_idx, out_sc);
}